// Round 1
// baseline (570.086 us; speedup 1.0000x reference)
//
#include <hip/hip_runtime.h>

// BitNet-style ternary matmul: y = (x @ round(W/mean|W|)^T) * mean|W|
// Pipeline: reduce |W| -> quantize W + cast x to bf16 -> bf16 MFMA GEMM.
//
// GEMM rewritten this round as the 256x256 8-phase template (learn_hip m201):
//   - BM=BN=256, BK=64, 512 threads = 8 waves (2M x 4N), per-wave C = 128x64
//   - LDS 128 KiB: 2 dbuf x 2 halves x [128][64] bf16 for A and B
//   - global_load_lds width=16, linear LDS dest + pre-swizzled global source
//     (chunk ^= row&7), ds_read side applies the same XOR -> conflict-free b128
//   - per K-tile: 4 phases {ds_read ; 1 half-tile stage ; barrier ; lgkmcnt(0) ;
//     setprio(1) ; 16 MFMA ; setprio(0) ; barrier}, ONE counted vmcnt(4)/K-tile
//   - stage schedule: A(j+1) @ phases 0/1 (other buffer), B(j+2) @ phases 2/3
//     (own buffer's dead B region). vmcnt(4) at phase 3 forces all of kt j+1
//     landed (leaves B(j+2) = 2 half-tiles in flight). Epilogue: vmcnt(0) once.
//   - XCD-aware bijective block swizzle (512 blocks / 8 XCDs = 64 per XCD).

#define K_DIM 4096
#define N_DIM 4096
#define NKT   64   // K_DIM / 64

typedef __bf16 bf16x8 __attribute__((ext_vector_type(8)));
typedef float floatx4 __attribute__((ext_vector_type(4)));

__device__ __forceinline__ unsigned short f32_to_bf16(float f) {
    unsigned int u = __float_as_uint(f);
    u += 0x7fffu + ((u >> 16) & 1u);   // round-to-nearest-even
    return (unsigned short)(u >> 16);
}

// ---------------- kernel 1a: per-block partial sums of |W| ----------------
__global__ void reduce_abs_p1(const float4* __restrict__ W, double* __restrict__ partials, int n4) {
    int tid = blockIdx.x * blockDim.x + threadIdx.x;
    int stride = gridDim.x * blockDim.x;
    float s = 0.f;
    for (int i = tid; i < n4; i += stride) {
        float4 v = W[i];
        s += fabsf(v.x) + fabsf(v.y) + fabsf(v.z) + fabsf(v.w);
    }
    double d = (double)s;
#pragma unroll
    for (int o = 32; o > 0; o >>= 1) d += __shfl_down(d, o, 64);
    __shared__ double lds[4];
    if ((threadIdx.x & 63) == 0) lds[threadIdx.x >> 6] = d;
    __syncthreads();
    if (threadIdx.x == 0)
        partials[blockIdx.x] = lds[0] + lds[1] + lds[2] + lds[3];
}

// ---------------- kernel 1b: final reduce of 1024 partials ----------------
__global__ void reduce_abs_p2(const double* __restrict__ partials, double* __restrict__ out) {
    double d = 0.0;
#pragma unroll
    for (int i = 0; i < 4; ++i) d += partials[threadIdx.x + i * 256];
#pragma unroll
    for (int o = 32; o > 0; o >>= 1) d += __shfl_down(d, o, 64);
    __shared__ double lds[4];
    if ((threadIdx.x & 63) == 0) lds[threadIdx.x >> 6] = d;
    __syncthreads();
    if (threadIdx.x == 0) *out = lds[0] + lds[1] + lds[2] + lds[3];
}

// ---------------- kernel 2: fused W-quantize + x-convert ----------------
__global__ void prep(const float4* __restrict__ W, const float4* __restrict__ X,
                     const double* __restrict__ sum,
                     ushort4* __restrict__ Wq, ushort4* __restrict__ Xb,
                     int nW4, int nX4, double inv_cnt) {
    float scale = (float)(*sum * inv_cnt);
    float d = scale + 1e-5f;
    int tid = blockIdx.x * blockDim.x + threadIdx.x;
    int stride = gridDim.x * blockDim.x;
    for (int i = tid; i < nW4; i += stride) {
        float4 v = W[i];
        ushort4 q;
        q.x = f32_to_bf16(rintf(v.x / d));   // IEEE divide + RNE == numpy round-half-even
        q.y = f32_to_bf16(rintf(v.y / d));
        q.z = f32_to_bf16(rintf(v.z / d));
        q.w = f32_to_bf16(rintf(v.w / d));
        Wq[i] = q;
    }
    for (int i = tid; i < nX4; i += stride) {
        float4 v = X[i];
        ushort4 q;
        q.x = f32_to_bf16(v.x);
        q.y = f32_to_bf16(v.y);
        q.z = f32_to_bf16(v.z);
        q.w = f32_to_bf16(v.w);
        Xb[i] = q;
    }
}

// ---------------- kernel 3: C[m,n] = scale * sum_k A[m,k]*B[n,k] ----------------
// 256x256 tile, BK=64, 8-phase schedule with counted vmcnt (see header comment).
__global__ __launch_bounds__(512, 2) void gemm_bt(
    const unsigned short* __restrict__ A, const unsigned short* __restrict__ B,
    float* __restrict__ C, const double* __restrict__ sum, double inv_cnt) {

    // [buf][half][128*64] bf16 = 16 KiB per half; total 128 KiB
    __shared__ __attribute__((aligned(16))) unsigned short As[2][2][128 * 64];
    __shared__ __attribute__((aligned(16))) unsigned short Bs[2][2][128 * 64];

    const int tid  = threadIdx.x;
    const int w    = tid >> 6;     // wave 0..7
    const int lane = tid & 63;
    const int wm   = w >> 2;       // 0..1  -> C rows wm*128..+128
    const int wn   = w & 3;        // 0..3  -> C cols wn*64..+64

    // XCD-aware bijective swizzle: 512 blocks, 8 XCDs, 64 blocks each.
    // Each XCD gets 4 consecutive M-panels x all N -> A panel (2 MB) L2-hot.
    const int bid = blockIdx.y * gridDim.x + blockIdx.x;
    const int swz = (bid & 7) * 64 + (bid >> 3);
    const size_t m0 = (size_t)(swz >> 4) * 256;
    const size_t n0 = (size_t)(swz & 15) * 256;

    // --- staging addressing -------------------------------------------------
    // One global_load_lds per wave = 64 lanes x 16 B = 8 rows x 128 B (linear
    // LDS dest).  lane -> row lane>>3, phys chunk lane&7.  The LDS image is
    // chunk-swizzled: phys chunk c holds global chunk c ^ (row&7), achieved by
    // pre-swizzling the per-lane GLOBAL source (dest stays linear, rule #21).
    const int srow   = lane >> 3;
    const int schunk = (lane & 7) ^ srow;
    const unsigned short* pA = A + (m0 + (size_t)(w * 8 + srow)) * K_DIM + schunk * 8;
    const unsigned short* pB = B + (n0 + (size_t)(w * 8 + srow)) * K_DIM + schunk * 8;

    // --- fragment read addressing (16x16x32 MFMA) ---------------------------
    // lane = (fm = lane&15, q = lane>>4); A frag: row = mf*16+fm, k = ks*32+q*8
    // logical chunk = ks*4+q; phys chunk = logical ^ (fm&7)  (row&7 == fm&7)
    const int fm    = lane & 15;
    const int q     = lane >> 4;
    const int cs0   = (q ^ (fm & 7)) * 8;          // ks=0, in shorts
    const int cs1   = ((4 + q) ^ (fm & 7)) * 8;    // ks=1
    const int abase = fm * 64;
    const int bh    = wn >> 1;                      // which B half this wave reads
    const int bbase = (wn & 1) * 4096 + fm * 64;    // row offset within the half

    floatx4 acc[8][4] = {};    // [m-frag][n-frag]
    bf16x8  afr[2][4];         // [ks][m-frag within current m-half]
    bf16x8  bfr[2][2][2];      // [n-half][ks][n-frag]

#define STAGE_A(bb, h, kt) do {                                                            \
        __builtin_amdgcn_global_load_lds(                                                  \
            (const __attribute__((address_space(1))) void*)(pA + ((h) * 128 + 0) * K_DIM + (kt) * 64), \
            (__attribute__((address_space(3))) void*)&As[bb][h][w * 512 + 0], 16, 0, 0);   \
        __builtin_amdgcn_global_load_lds(                                                  \
            (const __attribute__((address_space(1))) void*)(pA + ((h) * 128 + 64) * K_DIM + (kt) * 64), \
            (__attribute__((address_space(3))) void*)&As[bb][h][w * 512 + 4096], 16, 0, 0); \
    } while (0)

#define STAGE_B(bb, h, kt) do {                                                            \
        __builtin_amdgcn_global_load_lds(                                                  \
            (const __attribute__((address_space(1))) void*)(pB + ((h) * 128 + 0) * K_DIM + (kt) * 64), \
            (__attribute__((address_space(3))) void*)&Bs[bb][h][w * 512 + 0], 16, 0, 0);   \
        __builtin_amdgcn_global_load_lds(                                                  \
            (const __attribute__((address_space(1))) void*)(pB + ((h) * 128 + 64) * K_DIM + (kt) * 64), \
            (__attribute__((address_space(3))) void*)&Bs[bb][h][w * 512 + 4096], 16, 0, 0); \
    } while (0)

#define READ_A(b, mh) do {                                                                 \
        _Pragma("unroll")                                                                  \
        for (int t = 0; t < 4; ++t) {                                                      \
            afr[0][t] = *(const bf16x8*)&As[b][wm][((mh) * 4 + t) * 1024 + abase + cs0];   \
            afr[1][t] = *(const bf16x8*)&As[b][wm][((mh) * 4 + t) * 1024 + abase + cs1];   \
        }                                                                                  \
    } while (0)

#define READ_B(b, nh) do {                                                                 \
        _Pragma("unroll")                                                                  \
        for (int u = 0; u < 2; ++u) {                                                      \
            bfr[nh][0][u] = *(const bf16x8*)&Bs[b][bh][bbase + ((nh) * 2 + u) * 1024 + cs0]; \
            bfr[nh][1][u] = *(const bf16x8*)&Bs[b][bh][bbase + ((nh) * 2 + u) * 1024 + cs1]; \
        }                                                                                  \
    } while (0)

#define MFMA16(mh, nh) do {                                                                \
        _Pragma("unroll")                                                                  \
        for (int t = 0; t < 4; ++t)                                                        \
            _Pragma("unroll")                                                              \
            for (int u = 0; u < 2; ++u) {                                                  \
                acc[(mh) * 4 + t][(nh) * 2 + u] = __builtin_amdgcn_mfma_f32_16x16x32_bf16( \
                    afr[0][t], bfr[nh][0][u], acc[(mh) * 4 + t][(nh) * 2 + u], 0, 0, 0);   \
                acc[(mh) * 4 + t][(nh) * 2 + u] = __builtin_amdgcn_mfma_f32_16x16x32_bf16( \
                    afr[1][t], bfr[nh][1][u], acc[(mh) * 4 + t][(nh) * 2 + u], 0, 0, 0);   \
            }                                                                              \
    } while (0)

    // 4 phases per K-tile; quadrant order (mh,nh) = (0,0),(0,1),(1,0),(1,1).
    // ds_read counts per phase: 12, 4, 8, 0.  One counted vmcnt per K-tile.
#define KTILE(b, j, DOA, DOB, VMW) do {                                                    \
        /* phase 0 */                                                                      \
        READ_A(b, 0);                                                                      \
        READ_B(b, 0);                                                                      \
        if (DOA) STAGE_A((b) ^ 1, 0, (j) + 1);                                             \
        asm volatile("s_waitcnt lgkmcnt(8)" ::: "memory");                                 \
        __builtin_amdgcn_s_barrier();                                                      \
        asm volatile("s_waitcnt lgkmcnt(0)" ::: "memory");                                 \
        __builtin_amdgcn_s_setprio(1);                                                     \
        MFMA16(0, 0);                                                                      \
        __builtin_amdgcn_s_setprio(0);                                                     \
        __builtin_amdgcn_s_barrier();                                                      \
        /* phase 1 */                                                                      \
        READ_B(b, 1);                                                                      \
        if (DOA) STAGE_A((b) ^ 1, 1, (j) + 1);                                             \
        __builtin_amdgcn_s_barrier();                                                      \
        asm volatile("s_waitcnt lgkmcnt(0)" ::: "memory");                                 \
        __builtin_amdgcn_s_setprio(1);                                                     \
        MFMA16(0, 1);                                                                      \
        __builtin_amdgcn_s_setprio(0);                                                     \
        __builtin_amdgcn_s_barrier();                                                      \
        /* phase 2 */                                                                      \
        READ_A(b, 1);                                                                      \
        if (DOB) STAGE_B(b, 0, (j) + 2);                                                   \
        __builtin_amdgcn_s_barrier();                                                      \
        asm volatile("s_waitcnt lgkmcnt(0)" ::: "memory");                                 \
        __builtin_amdgcn_s_setprio(1);                                                     \
        MFMA16(1, 0);                                                                      \
        __builtin_amdgcn_s_setprio(0);                                                     \
        __builtin_amdgcn_s_barrier();                                                      \
        /* phase 3 */                                                                      \
        if (DOB) STAGE_B(b, 1, (j) + 2);                                                   \
        __builtin_amdgcn_s_barrier();                                                      \
        __builtin_amdgcn_s_setprio(1);                                                     \
        MFMA16(1, 1);                                                                      \
        __builtin_amdgcn_s_setprio(0);                                                     \
        asm volatile(VMW ::: "memory");                                                    \
        __builtin_amdgcn_s_barrier();                                                      \
    } while (0)

    // ---- prologue: kt0 (both A+B) -> buf0, B(kt1) -> buf1; force kt0 landed
    STAGE_B(0, 0, 0); STAGE_B(0, 1, 0);
    STAGE_A(0, 0, 0); STAGE_A(0, 1, 0);
    STAGE_B(1, 0, 1); STAGE_B(1, 1, 1);
    asm volatile("s_waitcnt vmcnt(4)" ::: "memory");
    __builtin_amdgcn_s_barrier();

    // ---- main loop: 2 K-tiles per iteration, compile-time buffer indices
    for (int j = 0; j < NKT - 2; j += 2) {
        KTILE(0, j,     1, 1, "s_waitcnt vmcnt(4)");
        KTILE(1, j + 1, 1, 1, "s_waitcnt vmcnt(4)");
    }
    // ---- epilogue: kt62 stages A(63), drains; kt63 stages nothing
    KTILE(0, NKT - 2, 1, 0, "s_waitcnt vmcnt(0)");
    KTILE(1, NKT - 1, 0, 0, "");

#undef KTILE
#undef MFMA16
#undef READ_B
#undef READ_A
#undef STAGE_B
#undef STAGE_A

    // ---- C write: C/D layout col = lane&15, row = (lane>>4)*4 + reg
    const float scale = (float)(*sum * inv_cnt);
    const size_t m0c = m0 + (size_t)wm * 128;
    const size_t n0c = n0 + (size_t)wn * 64;
#pragma unroll
    for (int mf = 0; mf < 8; ++mf) {
#pragma unroll
        for (int nf = 0; nf < 4; ++nf) {
            float* cp = C + (m0c + mf * 16 + q * 4) * N_DIM + n0c + nf * 16 + fm;
#pragma unroll
            for (int r = 0; r < 4; ++r)
                cp[(size_t)r * N_DIM] = acc[mf][nf][r] * scale;
        }
    }
}

extern "C" void kernel_launch(void* const* d_in, const int* in_sizes, int n_in,
                              void* d_out, int out_size, void* d_ws, size_t ws_size,
                              hipStream_t stream) {
    const float* x = (const float*)d_in[0];
    const float* W = (const float*)d_in[1];
    float* y = (float*)d_out;

    const int nW = in_sizes[1];            // 4096*4096
    const int M  = in_sizes[0] / K_DIM;    // 8192

    double* d_sum = (double*)d_ws;
    double* d_partials = (double*)((char*)d_ws + 16);
    unsigned short* xb = (unsigned short*)((char*)d_ws + 16 + 1024 * sizeof(double));
    unsigned short* wq = xb + (size_t)M * K_DIM;
    const double inv_cnt = 1.0 / (double)nW;

    reduce_abs_p1<<<1024, 256, 0, stream>>>((const float4*)W, d_partials, nW / 4);
    reduce_abs_p2<<<1, 256, 0, stream>>>(d_partials, d_sum);
    prep<<<2048, 256, 0, stream>>>((const float4*)W, (const float4*)x, d_sum,
                                   (ushort4*)wq, (ushort4*)xb,
                                   nW / 4, in_sizes[0] / 4, inv_cnt);

    dim3 grid(N_DIM / 256, M / 256);       // 16 x 32 = 512 blocks
    gemm_bt<<<grid, 512, 0, stream>>>(xb, wq, y, d_sum, inv_cnt);
}